// Round 15
// baseline (95.826 us; speedup 1.0000x reference)
//
#include <hip/hip_runtime.h>
#include <math.h>

// ===== MEASUREMENT ROUND: r14 config + duplicated k_nms node =====
// Purpose: dur_us(this) - dur_us(r14) = t(k_nms) + one inter-node gap.
// k_nms is idempotent (same inputs -> same klist/kcnt), so the dup is safe.

#define BB 16
#define NN 2048
#define CCH 81
#define GG 16
#define NCLS 80
#define SLOTS 64

typedef unsigned long long u64;
typedef unsigned int u32;
typedef float f4_t __attribute__((ext_vector_type(4)));
typedef f4_t uf4 __attribute__((aligned(4)));   // logit rows are only 4B-aligned

__device__ __forceinline__ float iou4(float4 a, float4 b) {
    float areaA = (a.z - a.x) * (a.w - a.y);
    float areaB = (b.z - b.x) * (b.w - b.y);
    float ltx = fmaxf(a.x, b.x), lty = fmaxf(a.y, b.y);
    float rbx = fminf(a.z, b.z), rby = fminf(a.w, b.w);
    float w = fmaxf(rbx - ltx, 0.0f), h = fmaxf(rby - lty, 0.0f);
    float inter = w * h;
    return inter / (areaA + areaB - inter + 1e-9f);
}

__global__ void __launch_bounds__(256) k_perbox(const float* __restrict__ boxes,
                                                const float* __restrict__ logits,
                                                const float* __restrict__ gtb,
                                                const int* __restrict__ gtc,
                                                float* __restrict__ score,
                                                float* __restrict__ ce,
                                                unsigned char* __restrict__ label,
                                                u32* __restrict__ done) {
    int tid = threadIdx.x;
    int q = tid & 7;
    int gid = blockIdx.x * 32 + (tid >> 3);
    int b = gid >> 11;
    if (blockIdx.x == 0 && tid == 0) *done = 0;

    float4 bx = ((const float4*)boxes)[gid];
    float best = -1.0f;
    int bg = 0x7FFFFFFF;
    for (int g = q; g < GG; g += 8) {
        float4 gb = ((const float4*)gtb)[b * GG + g];
        float v = iou4(bx, gb);
        if (v > best) { best = v; bg = g; }   // ascending g: strict > = earliest
    }
    for (int d = 1; d < 8; d <<= 1) {
        float vo = __shfl_xor(best, d);
        int go = __shfl_xor(bg, d);
        if (vo > best || (vo == best && go < bg)) { best = vo; bg = go; }
    }
    int assigned = (best >= 0.5f) ? gtc[b * GG + bg] : 80;

    const float* lg = logits + (size_t)gid * CCH;
    uf4 v0 = *(const uf4*)(lg + 4 * q);
    uf4 v1 = *(const uf4*)(lg + 32 + 4 * q);
    bool has2 = (q < 4);
    uf4 v2 = v0;
    if (has2) v2 = *(const uf4*)(lg + 64 + 4 * q);
    float v80 = (q == 7) ? lg[80] : -INFINITY;

    float m = v80, m80 = -INFINITY, la = 0.0f;
    int arg = 0x7FFFFFFF;
    #pragma unroll
    for (int k = 0; k < 4; ++k) {
        float a0 = v0[k]; int c0 = 4 * q + k;
        m = fmaxf(m, a0);
        if (a0 > m80) { m80 = a0; arg = c0; }
        if (c0 == assigned) la = a0;
    }
    #pragma unroll
    for (int k = 0; k < 4; ++k) {
        float a1 = v1[k]; int c1 = 32 + 4 * q + k;
        m = fmaxf(m, a1);
        if (a1 > m80) { m80 = a1; arg = c1; }
        if (c1 == assigned) la = a1;
    }
    if (has2) {
        #pragma unroll
        for (int k = 0; k < 4; ++k) {
            float a2 = v2[k]; int c2 = 64 + 4 * q + k;
            m = fmaxf(m, a2);
            if (a2 > m80) { m80 = a2; arg = c2; }
            if (c2 == assigned) la = a2;
        }
    }
    if (q == 7 && assigned == 80) la = v80;

    for (int d = 1; d < 8; d <<= 1) m = fmaxf(m, __shfl_xor(m, d));

    float s = (q == 7) ? __expf(v80 - m) : 0.0f;
    #pragma unroll
    for (int k = 0; k < 4; ++k) s += __expf(v0[k] - m) + __expf(v1[k] - m);
    if (has2) {
        #pragma unroll
        for (int k = 0; k < 4; ++k) s += __expf(v2[k] - m);
    }
    for (int d = 1; d < 8; d <<= 1) {
        s += __shfl_xor(s, d);
        float m80o = __shfl_xor(m80, d);
        int argo = __shfl_xor(arg, d);
        if (m80o > m80 || (m80o == m80 && argo < arg)) { m80 = m80o; arg = argo; }
        la += __shfl_xor(la, d);
    }
    if (q == 0) {
        float sc = __expf(m80 - m) / s;
        ce[gid] = (m + __logf(s)) - la;
        score[gid] = sc;
        label[gid] = (sc >= 0.05f) ? (unsigned char)arg : (unsigned char)0xFF;
    }
}

__global__ void __launch_bounds__(64) k_nms(const float* __restrict__ boxes,
                                            const float* __restrict__ score,
                                            const unsigned char* __restrict__ label,
                                            u64* __restrict__ klist,
                                            u32* __restrict__ kcnt) {
    int b = blockIdx.x / NCLS;
    int c = blockIdx.x % NCLS;
    int lane = threadIdx.x;

    const u32* lab32 = (const u32*)(label + b * NN);
    u64 key0 = 0, key1 = 0;                  // element e = slot*64 + lane
    int k = 0;
    for (int chunk = 0; chunk < NN; chunk += 256) {
        u32 lv = lab32[(chunk >> 2) + lane];
        #pragma unroll
        for (int jj = 0; jj < 4; ++jj) {
            bool match = (((lv >> (8 * jj)) & 0xFFu) == (u32)c);
            u64 mk = 0;
            if (match) {
                int i = chunk + 4 * lane + jj;
                mk = ((u64)(__float_as_uint(score[b * NN + i]) | 0x80000000u) << 32) |
                     (u64)(0xFFFFFFFFu - (u32)i);
            }
            u64 mask = __ballot(match);
            while (mask) {
                int j = __ffsll(mask) - 1;
                mask &= mask - 1;
                u64 kv = __shfl(mk, j);
                if (k < 128 && (k & 63) == lane) {
                    if (k < 64) key0 = kv; else key1 = kv;
                }
                ++k;
            }
        }
    }
    if (k > 128) k = 128;

    u64 m0 = 0, m1 = 0;
    if (k > 0) {
        for (int kk = 2; kk <= 128; kk <<= 1) {
            for (int j = kk >> 1; j > 0; j >>= 1) {
                if (j == 64) {
                    u64 lo = key0 >= key1 ? key0 : key1;
                    u64 hi = key0 >= key1 ? key1 : key0;
                    key0 = lo; key1 = hi;
                } else {
                    bool lower = (lane & j) == 0;
                    bool dir0 = ((lane & kk) == 0);
                    bool dir1 = (((64 + lane) & kk) == 0);
                    u64 p0 = __shfl_xor(key0, j);
                    u64 p1 = __shfl_xor(key1, j);
                    bool t0 = lower ? (dir0 ? (p0 > key0) : (p0 < key0))
                                    : (dir0 ? (p0 < key0) : (p0 > key0));
                    bool t1 = lower ? (dir1 ? (p1 > key1) : (p1 < key1))
                                    : (dir1 ? (p1 < key1) : (p1 > key1));
                    if (t0) key0 = p0;
                    if (t1) key1 = p1;
                }
            }
        }
        bool val0 = lane < k;
        bool val1 = (64 + lane) < k;
        u32 idx0 = 0xFFFFFFFFu - (u32)(key0 & 0xFFFFFFFFull);
        u32 idx1 = 0xFFFFFFFFu - (u32)(key1 & 0xFFFFFFFFull);
        float4 B0 = val0 ? ((const float4*)boxes)[b * NN + idx0]
                         : make_float4(0.f, 0.f, 0.f, 0.f);
        float4 B1 = val1 ? ((const float4*)boxes)[b * NN + idx1]
                         : make_float4(0.f, 0.f, 0.f, 0.f);
        bool sup0 = false, sup1 = false;
        for (int i = 0; i < k; ++i) {
            u64 sm0 = __ballot(sup0);
            u64 sm1 = __ballot(sup1);
            bool supi = (i < 64) ? ((sm0 >> i) & 1ull) : ((sm1 >> (i - 64)) & 1ull);
            if (supi) continue;              // uniform (from ballots)
            int sl = i & 63;
            float ax = __shfl(i < 64 ? B0.x : B1.x, sl);
            float ay = __shfl(i < 64 ? B0.y : B1.y, sl);
            float az = __shfl(i < 64 ? B0.z : B1.z, sl);
            float aw = __shfl(i < 64 ? B0.w : B1.w, sl);
            float4 A; A.x = ax; A.y = ay; A.z = az; A.w = aw;
            if (val0 && lane > i && !sup0 && iou4(A, B0) > 0.5f) sup0 = true;
            if (val1 && (64 + lane) > i && !sup1 && iou4(A, B1) > 0.5f) sup1 = true;
        }
        m0 = __ballot(val0 && !sup0);
        m1 = __ballot(val1 && !sup1);
    }

    u64 below = (1ull << lane) - 1ull;
    int kept0 = __popcll(m0);
    u64* dst = klist + (size_t)(b * NCLS + c) * SLOTS;
    if ((m0 >> lane) & 1ull) {
        int r = __popcll(m0 & below);
        if (r < SLOTS) dst[r] = key0;
    }
    if ((m1 >> lane) & 1ull) {
        int r = kept0 + __popcll(m1 & below);
        if (r < SLOTS) dst[r] = key1;
    }
    if (lane == 0) {
        int tot = kept0 + __popcll(m1);
        kcnt[b * NCLS + c] = (u32)(tot < SLOTS ? tot : SLOTS);
    }
}

__global__ void __launch_bounds__(256) k_select(const u64* __restrict__ klist,
                                                const u32* __restrict__ kcnt,
                                                const float* __restrict__ ce,
                                                float* __restrict__ partial,
                                                u32* __restrict__ done,
                                                float* __restrict__ out) {
    __shared__ u64 skey[NN];
    __shared__ int cnts_s[NCLS];
    __shared__ int base_s[NCLS];
    __shared__ int ntot;
    __shared__ u64 wmax[4];
    __shared__ int wslot[4];
    int b = blockIdx.x;
    int tid = threadIdx.x;
    int lane = tid & 63, wid = tid >> 6;

    if (tid < NCLS) cnts_s[tid] = (int)kcnt[b * NCLS + tid];
    __syncthreads();
    if (tid == 0) {
        int acc = 0;
        for (int c = 1; c < NCLS; ++c) { base_s[c] = acc; acc += cnts_s[c]; }
        ntot = acc;
    }
    __syncthreads();
    int n = ntot;
    int hc = cnts_s[0];
    int hm = hc < 10 ? hc : 10;

    for (int idx = tid; idx < (NCLS - 1) * SLOTS; idx += 256) {
        int c = 1 + (idx >> 6), s = idx & (SLOTS - 1);
        if (s < cnts_s[c])
            skey[base_s[c] + s] = klist[(size_t)(b * NCLS + c) * SLOTS + s];
    }

    float hsum = 0.0f;
    {
        float hv = 0.0f;
        if (tid < hm) {
            u32 idx = 0xFFFFFFFFu -
                      (u32)(klist[(size_t)(b * NCLS) * SLOTS + tid] & 0xFFFFFFFFull);
            hv = ce[b * NN + idx];
        }
        if (wid == 0)
            for (int r = 0; r < hm; ++r) hsum += __shfl(hv, r);  // descending order
    }
    __syncthreads();

    int om = n < 10 ? n : 10;
    float osum = 0.0f;
    if (om > 0) {
        u64 ck = 0; int cs = -1;
        for (int s = tid; s < n; s += 256) {
            u64 v = skey[s];
            if (v > ck) { ck = v; cs = s; }
        }
        for (int t = 0; t < om; ++t) {
            u64 k2 = ck; int s2 = cs;
            for (int d = 1; d < 64; d <<= 1) {
                u64 ok = __shfl_xor(k2, d);
                int os = __shfl_xor(s2, d);
                if (ok > k2) { k2 = ok; s2 = os; }
            }
            if (lane == 0) { wmax[wid] = k2; wslot[wid] = s2; }
            __syncthreads();
            u64 bk = wmax[0]; int bs = wslot[0];
            for (int w = 1; w < 4; ++w)
                if (wmax[w] > bk) { bk = wmax[w]; bs = wslot[w]; }
            u32 idx = 0xFFFFFFFFu - (u32)(bk & 0xFFFFFFFFull);
            osum += ce[b * NN + idx];
            if (cs == bs) {
                skey[bs] = 0;
                ck = 0; cs = -1;
                for (int s = tid; s < n; s += 256) {
                    u64 v = skey[s];
                    if (v > ck) { ck = v; cs = s; }
                }
            }
            __syncthreads();
        }
    }

    if (tid == 0) {
        ((volatile float*)partial)[b * 2 + 0] = hsum + osum;
        ((volatile float*)partial)[b * 2 + 1] = (float)(hm + om);
        __threadfence();
        u32 t = atomicAdd(done, 1u);
        if (t == BB - 1) {
            __threadfence();
            float cs2 = 0.0f, cn = 0.0f;
            for (int i = 0; i < BB; ++i) {
                cs2 += ((volatile float*)partial)[i * 2 + 0];
                cn += ((volatile float*)partial)[i * 2 + 1];
            }
            out[0] = cs2 / fmaxf(cn, 1.0f);
        }
    }
}

extern "C" void kernel_launch(void* const* d_in, const int* in_sizes, int n_in,
                              void* d_out, int out_size, void* d_ws, size_t ws_size,
                              hipStream_t stream) {
    const float* boxes = (const float*)d_in[0];       // (16,2048,4)
    const float* logits = (const float*)d_in[1];      // (16,2048,81)
    const float* gt_boxes = (const float*)d_in[2];    // (16,16,4)
    const int* gt_classes = (const int*)d_in[3];      // (16,16)
    float* out = (float*)d_out;

    char* ws = (char*)d_ws;
    size_t off = 0;
    auto alloc = [&](size_t bytes) {
        char* p = ws + off;
        off = (off + bytes + 255) & ~(size_t)255;
        return p;
    };
    float* score = (float*)alloc(BB * NN * sizeof(float));
    float* ce = (float*)alloc(BB * NN * sizeof(float));
    unsigned char* label = (unsigned char*)alloc(BB * NN);
    u64* klist = (u64*)alloc((size_t)BB * NCLS * SLOTS * sizeof(u64));
    u32* kcnt = (u32*)alloc(BB * NCLS * sizeof(u32));
    float* partial = (float*)alloc(BB * 2 * sizeof(float));
    u32* done = (u32*)alloc(sizeof(u32));

    k_perbox<<<BB * NN / 32, 256, 0, stream>>>(boxes, logits, gt_boxes, gt_classes,
                                               score, ce, label, done);
    k_nms<<<BB * NCLS, 64, 0, stream>>>(boxes, score, label, klist, kcnt);
    // MEASUREMENT: duplicated, idempotent. dur_us delta vs r14 = t(k_nms) + gap.
    k_nms<<<BB * NCLS, 64, 0, stream>>>(boxes, score, label, klist, kcnt);
    k_select<<<BB, 256, 0, stream>>>(klist, kcnt, ce, partial, done, out);
}

// Round 16
// 51.040 us; speedup vs baseline: 1.8775x; 1.8775x over previous
//
#include <hip/hip_runtime.h>
#include <math.h>

#define BB 16
#define NN 2048
#define CCH 81
#define GG 16
#define NCLS 80
#define SLOTS 64

typedef unsigned long long u64;
typedef unsigned int u32;
typedef float f4_t __attribute__((ext_vector_type(4)));
typedef f4_t uf4 __attribute__((aligned(4)));   // logit rows are only 4B-aligned

__device__ __forceinline__ float iou4(float4 a, float4 b) {
    float areaA = (a.z - a.x) * (a.w - a.y);
    float areaB = (b.z - b.x) * (b.w - b.y);
    float ltx = fmaxf(a.x, b.x), lty = fmaxf(a.y, b.y);
    float rbx = fminf(a.z, b.z), rby = fminf(a.w, b.w);
    float w = fmaxf(rbx - ltx, 0.0f), h = fmaxf(rby - lty, 0.0f);
    float inter = w * h;
    return inter / (areaA + areaB - inter + 1e-9f);
}

// Kernel 1 (unchanged from r14): 8 threads/box, float4 logit loads.
__global__ void __launch_bounds__(256) k_perbox(const float* __restrict__ boxes,
                                                const float* __restrict__ logits,
                                                const float* __restrict__ gtb,
                                                const int* __restrict__ gtc,
                                                float* __restrict__ score,
                                                float* __restrict__ ce,
                                                unsigned char* __restrict__ label,
                                                u32* __restrict__ done) {
    int tid = threadIdx.x;
    int q = tid & 7;
    int gid = blockIdx.x * 32 + (tid >> 3);
    int b = gid >> 11;
    if (blockIdx.x == 0 && tid == 0) *done = 0;

    float4 bx = ((const float4*)boxes)[gid];
    float best = -1.0f;
    int bg = 0x7FFFFFFF;
    for (int g = q; g < GG; g += 8) {
        float4 gb = ((const float4*)gtb)[b * GG + g];
        float v = iou4(bx, gb);
        if (v > best) { best = v; bg = g; }   // ascending g: strict > = earliest
    }
    for (int d = 1; d < 8; d <<= 1) {
        float vo = __shfl_xor(best, d);
        int go = __shfl_xor(bg, d);
        if (vo > best || (vo == best && go < bg)) { best = vo; bg = go; }
    }
    int assigned = (best >= 0.5f) ? gtc[b * GG + bg] : 80;

    const float* lg = logits + (size_t)gid * CCH;
    uf4 v0 = *(const uf4*)(lg + 4 * q);
    uf4 v1 = *(const uf4*)(lg + 32 + 4 * q);
    bool has2 = (q < 4);
    uf4 v2 = v0;
    if (has2) v2 = *(const uf4*)(lg + 64 + 4 * q);
    float v80 = (q == 7) ? lg[80] : -INFINITY;

    float m = v80, m80 = -INFINITY, la = 0.0f;
    int arg = 0x7FFFFFFF;
    #pragma unroll
    for (int k = 0; k < 4; ++k) {
        float a0 = v0[k]; int c0 = 4 * q + k;
        m = fmaxf(m, a0);
        if (a0 > m80) { m80 = a0; arg = c0; }
        if (c0 == assigned) la = a0;
    }
    #pragma unroll
    for (int k = 0; k < 4; ++k) {
        float a1 = v1[k]; int c1 = 32 + 4 * q + k;
        m = fmaxf(m, a1);
        if (a1 > m80) { m80 = a1; arg = c1; }
        if (c1 == assigned) la = a1;
    }
    if (has2) {
        #pragma unroll
        for (int k = 0; k < 4; ++k) {
            float a2 = v2[k]; int c2 = 64 + 4 * q + k;
            m = fmaxf(m, a2);
            if (a2 > m80) { m80 = a2; arg = c2; }
            if (c2 == assigned) la = a2;
        }
    }
    if (q == 7 && assigned == 80) la = v80;

    for (int d = 1; d < 8; d <<= 1) m = fmaxf(m, __shfl_xor(m, d));

    float s = (q == 7) ? __expf(v80 - m) : 0.0f;
    #pragma unroll
    for (int k = 0; k < 4; ++k) s += __expf(v0[k] - m) + __expf(v1[k] - m);
    if (has2) {
        #pragma unroll
        for (int k = 0; k < 4; ++k) s += __expf(v2[k] - m);
    }
    for (int d = 1; d < 8; d <<= 1) {
        s += __shfl_xor(s, d);
        float m80o = __shfl_xor(m80, d);
        int argo = __shfl_xor(arg, d);
        if (m80o > m80 || (m80o == m80 && argo < arg)) { m80 = m80o; arg = argo; }
        la += __shfl_xor(la, d);
    }
    if (q == 0) {
        float sc = __expf(m80 - m) / s;
        ce[gid] = (m + __logf(s)) - la;
        score[gid] = sc;
        label[gid] = (sc >= 0.05f) ? (unsigned char)arg : (unsigned char)0xFF;
    }
}

// Kernel 2 REWORKED: one wave per (image,class).
//  - upfront coalesced label+score loads (no scattered gathers in the chain)
//  - scan-based candidate collection via LDS (order-free: keys carry the
//    total order, the bitonic sort imposes it)
//  - fast path for k<=64 (always, statistically): 21-step sort, light loop
__global__ void __launch_bounds__(64) k_nms(const float* __restrict__ boxes,
                                            const float* __restrict__ score,
                                            const unsigned char* __restrict__ label,
                                            u64* __restrict__ klist,
                                            u32* __restrict__ kcnt) {
    __shared__ u64 cand[128];
    int b = blockIdx.x / NCLS;
    int c = blockIdx.x % NCLS;
    int lane = threadIdx.x;

    // upfront coalesced loads: 8 label words + 8 score float4 per lane
    const u32* lab32 = (const u32*)(label + b * NN);
    const float4* sc4 = (const float4*)(score + b * NN);
    u32 lw[8];
    float4 sw[8];
    #pragma unroll
    for (int ch = 0; ch < 8; ++ch) {
        int w = ch * 64 + lane;
        lw[ch] = lab32[w];
        sw[ch] = sc4[w];
    }

    // per-lane match count -> exclusive scan -> LDS scatter
    int cntl = 0;
    #pragma unroll
    for (int ch = 0; ch < 8; ++ch)
        #pragma unroll
        for (int jj = 0; jj < 4; ++jj)
            cntl += (((lw[ch] >> (8 * jj)) & 0xFFu) == (u32)c) ? 1 : 0;
    int incl = cntl;
    for (int d = 1; d < 64; d <<= 1) {
        int o = __shfl_up(incl, d);
        if (lane >= d) incl += o;
    }
    int k = __shfl(incl, 63);
    int off = incl - cntl;                   // exclusive prefix
    #pragma unroll
    for (int ch = 0; ch < 8; ++ch) {
        int w = ch * 64 + lane;
        #pragma unroll
        for (int jj = 0; jj < 4; ++jj) {
            if (((lw[ch] >> (8 * jj)) & 0xFFu) == (u32)c) {
                int i = 4 * w + jj;
                float sv = (jj == 0) ? sw[ch].x : (jj == 1) ? sw[ch].y
                         : (jj == 2) ? sw[ch].z : sw[ch].w;
                if (off < 128)
                    cand[off] = ((u64)(__float_as_uint(sv) | 0x80000000u) << 32) |
                                (u64)(0xFFFFFFFFu - (u32)i);
                ++off;
            }
        }
    }
    if (k > 128) k = 128;
    __syncthreads();                         // LDS scatter -> cross-lane reads

    u64 m0 = 0, m1 = 0;
    u64 key0 = 0, key1 = 0;
    if (k > 0 && k <= 64) {
        // ---------- fast path ----------
        key0 = (lane < k) ? cand[lane] : 0;
        for (int kk = 2; kk <= 64; kk <<= 1) {
            for (int j = kk >> 1; j > 0; j >>= 1) {
                bool lower = (lane & j) == 0;
                bool dir = ((lane & kk) == 0);
                u64 p = __shfl_xor(key0, j);
                bool t = lower ? (dir ? (p > key0) : (p < key0))
                               : (dir ? (p < key0) : (p > key0));
                if (t) key0 = p;
            }
        }
        bool val0 = lane < k;
        u32 idx0 = 0xFFFFFFFFu - (u32)(key0 & 0xFFFFFFFFull);
        float4 B0 = val0 ? ((const float4*)boxes)[b * NN + idx0]
                         : make_float4(0.f, 0.f, 0.f, 0.f);
        bool sup0 = false;
        for (int i = 0; i < k - 1; ++i) {
            u64 sm0 = __ballot(sup0);
            if ((sm0 >> i) & 1ull) continue;  // uniform
            float4 A;
            A.x = __shfl(B0.x, i); A.y = __shfl(B0.y, i);
            A.z = __shfl(B0.z, i); A.w = __shfl(B0.w, i);
            if (val0 && lane > i && !sup0 && iou4(A, B0) > 0.5f) sup0 = true;
        }
        m0 = __ballot(val0 && !sup0);
    } else if (k > 64) {
        // ---------- slow path (statistically never; correctness only) ----------
        key0 = cand[lane];
        key1 = (64 + lane < k) ? cand[64 + lane] : 0;
        for (int kk = 2; kk <= 128; kk <<= 1) {
            for (int j = kk >> 1; j > 0; j >>= 1) {
                if (j == 64) {
                    u64 lo = key0 >= key1 ? key0 : key1;
                    u64 hi = key0 >= key1 ? key1 : key0;
                    key0 = lo; key1 = hi;
                } else {
                    bool lower = (lane & j) == 0;
                    bool dir0 = ((lane & kk) == 0);
                    bool dir1 = (((64 + lane) & kk) == 0);
                    u64 p0 = __shfl_xor(key0, j);
                    u64 p1 = __shfl_xor(key1, j);
                    bool t0 = lower ? (dir0 ? (p0 > key0) : (p0 < key0))
                                    : (dir0 ? (p0 < key0) : (p0 > key0));
                    bool t1 = lower ? (dir1 ? (p1 > key1) : (p1 < key1))
                                    : (dir1 ? (p1 < key1) : (p1 > key1));
                    if (t0) key0 = p0;
                    if (t1) key1 = p1;
                }
            }
        }
        bool val0 = true;                    // lane < 64 <= k
        bool val1 = (64 + lane) < k;
        u32 idx0 = 0xFFFFFFFFu - (u32)(key0 & 0xFFFFFFFFull);
        u32 idx1 = 0xFFFFFFFFu - (u32)(key1 & 0xFFFFFFFFull);
        float4 B0 = ((const float4*)boxes)[b * NN + idx0];
        float4 B1 = val1 ? ((const float4*)boxes)[b * NN + idx1]
                         : make_float4(0.f, 0.f, 0.f, 0.f);
        bool sup0 = false, sup1 = false;
        for (int i = 0; i < k; ++i) {
            u64 sm0 = __ballot(sup0);
            u64 sm1 = __ballot(sup1);
            bool supi = (i < 64) ? ((sm0 >> i) & 1ull) : ((sm1 >> (i - 64)) & 1ull);
            if (supi) continue;              // uniform
            int sl = i & 63;
            float ax = __shfl(i < 64 ? B0.x : B1.x, sl);
            float ay = __shfl(i < 64 ? B0.y : B1.y, sl);
            float az = __shfl(i < 64 ? B0.z : B1.z, sl);
            float aw = __shfl(i < 64 ? B0.w : B1.w, sl);
            float4 A; A.x = ax; A.y = ay; A.z = az; A.w = aw;
            if (val0 && lane > i && !sup0 && iou4(A, B0) > 0.5f) sup0 = true;
            if (val1 && (64 + lane) > i && !sup1 && iou4(A, B1) > 0.5f) sup1 = true;
        }
        m0 = __ballot(val0 && !sup0);
        m1 = __ballot(val1 && !sup1);
    }

    // fixed-slot output: kept keys in descending order, plain stores
    u64 below = (1ull << lane) - 1ull;
    int kept0 = __popcll(m0);
    u64* dst = klist + (size_t)(b * NCLS + c) * SLOTS;
    if ((m0 >> lane) & 1ull) {
        int r = __popcll(m0 & below);
        if (r < SLOTS) dst[r] = key0;
    }
    if ((m1 >> lane) & 1ull) {
        int r = kept0 + __popcll(m1 & below);
        if (r < SLOTS) dst[r] = key1;
    }
    if (lane == 0) {
        int tot = kept0 + __popcll(m1);
        kcnt[b * NCLS + c] = (u32)(tot < SLOTS ? tot : SLOTS);
    }
}

// Kernel 3 (unchanged from r14): per-image select + final reduce.
__global__ void __launch_bounds__(256) k_select(const u64* __restrict__ klist,
                                                const u32* __restrict__ kcnt,
                                                const float* __restrict__ ce,
                                                float* __restrict__ partial,
                                                u32* __restrict__ done,
                                                float* __restrict__ out) {
    __shared__ u64 skey[NN];
    __shared__ int cnts_s[NCLS];
    __shared__ int base_s[NCLS];
    __shared__ int ntot;
    __shared__ u64 wmax[4];
    __shared__ int wslot[4];
    int b = blockIdx.x;
    int tid = threadIdx.x;
    int lane = tid & 63, wid = tid >> 6;

    if (tid < NCLS) cnts_s[tid] = (int)kcnt[b * NCLS + tid];
    __syncthreads();
    if (tid == 0) {
        int acc = 0;
        for (int c = 1; c < NCLS; ++c) { base_s[c] = acc; acc += cnts_s[c]; }
        ntot = acc;
    }
    __syncthreads();
    int n = ntot;
    int hc = cnts_s[0];
    int hm = hc < 10 ? hc : 10;

    for (int idx = tid; idx < (NCLS - 1) * SLOTS; idx += 256) {
        int c = 1 + (idx >> 6), s = idx & (SLOTS - 1);
        if (s < cnts_s[c])
            skey[base_s[c] + s] = klist[(size_t)(b * NCLS + c) * SLOTS + s];
    }

    float hsum = 0.0f;
    {
        float hv = 0.0f;
        if (tid < hm) {
            u32 idx = 0xFFFFFFFFu -
                      (u32)(klist[(size_t)(b * NCLS) * SLOTS + tid] & 0xFFFFFFFFull);
            hv = ce[b * NN + idx];
        }
        if (wid == 0)
            for (int r = 0; r < hm; ++r) hsum += __shfl(hv, r);  // descending order
    }
    __syncthreads();

    int om = n < 10 ? n : 10;
    float osum = 0.0f;
    if (om > 0) {
        u64 ck = 0; int cs = -1;
        for (int s = tid; s < n; s += 256) {
            u64 v = skey[s];
            if (v > ck) { ck = v; cs = s; }
        }
        for (int t = 0; t < om; ++t) {
            u64 k2 = ck; int s2 = cs;
            for (int d = 1; d < 64; d <<= 1) {
                u64 ok = __shfl_xor(k2, d);
                int os = __shfl_xor(s2, d);
                if (ok > k2) { k2 = ok; s2 = os; }
            }
            if (lane == 0) { wmax[wid] = k2; wslot[wid] = s2; }
            __syncthreads();
            u64 bk = wmax[0]; int bs = wslot[0];
            for (int w = 1; w < 4; ++w)
                if (wmax[w] > bk) { bk = wmax[w]; bs = wslot[w]; }
            u32 idx = 0xFFFFFFFFu - (u32)(bk & 0xFFFFFFFFull);
            osum += ce[b * NN + idx];
            if (cs == bs) {
                skey[bs] = 0;
                ck = 0; cs = -1;
                for (int s = tid; s < n; s += 256) {
                    u64 v = skey[s];
                    if (v > ck) { ck = v; cs = s; }
                }
            }
            __syncthreads();
        }
    }

    if (tid == 0) {
        ((volatile float*)partial)[b * 2 + 0] = hsum + osum;
        ((volatile float*)partial)[b * 2 + 1] = (float)(hm + om);
        __threadfence();
        u32 t = atomicAdd(done, 1u);
        if (t == BB - 1) {
            __threadfence();
            float cs2 = 0.0f, cn = 0.0f;
            for (int i = 0; i < BB; ++i) {
                cs2 += ((volatile float*)partial)[i * 2 + 0];
                cn += ((volatile float*)partial)[i * 2 + 1];
            }
            out[0] = cs2 / fmaxf(cn, 1.0f);
        }
    }
}

extern "C" void kernel_launch(void* const* d_in, const int* in_sizes, int n_in,
                              void* d_out, int out_size, void* d_ws, size_t ws_size,
                              hipStream_t stream) {
    const float* boxes = (const float*)d_in[0];       // (16,2048,4)
    const float* logits = (const float*)d_in[1];      // (16,2048,81)
    const float* gt_boxes = (const float*)d_in[2];    // (16,16,4)
    const int* gt_classes = (const int*)d_in[3];      // (16,16)
    float* out = (float*)d_out;

    char* ws = (char*)d_ws;
    size_t off = 0;
    auto alloc = [&](size_t bytes) {
        char* p = ws + off;
        off = (off + bytes + 255) & ~(size_t)255;
        return p;
    };
    float* score = (float*)alloc(BB * NN * sizeof(float));
    float* ce = (float*)alloc(BB * NN * sizeof(float));
    unsigned char* label = (unsigned char*)alloc(BB * NN);
    u64* klist = (u64*)alloc((size_t)BB * NCLS * SLOTS * sizeof(u64));
    u32* kcnt = (u32*)alloc(BB * NCLS * sizeof(u32));
    float* partial = (float*)alloc(BB * 2 * sizeof(float));
    u32* done = (u32*)alloc(sizeof(u32));

    k_perbox<<<BB * NN / 32, 256, 0, stream>>>(boxes, logits, gt_boxes, gt_classes,
                                               score, ce, label, done);
    k_nms<<<BB * NCLS, 64, 0, stream>>>(boxes, score, label, klist, kcnt);
    k_select<<<BB, 256, 0, stream>>>(klist, kcnt, ce, partial, done, out);
}

// Round 17
// 50.505 us; speedup vs baseline: 1.8974x; 1.0106x over previous
//
#include <hip/hip_runtime.h>
#include <math.h>

#define BB 16
#define NN 2048
#define CCH 81
#define GG 16
#define NCLS 80
#define SLOTS 64

typedef unsigned long long u64;
typedef unsigned int u32;
typedef unsigned short u16;
typedef float f4_t __attribute__((ext_vector_type(4)));
typedef f4_t uf4 __attribute__((aligned(4)));   // logit rows are only 4B-aligned

__device__ __forceinline__ float iou4(float4 a, float4 b) {
    float areaA = (a.z - a.x) * (a.w - a.y);
    float areaB = (b.z - b.x) * (b.w - b.y);
    float ltx = fmaxf(a.x, b.x), lty = fmaxf(a.y, b.y);
    float rbx = fminf(a.z, b.z), rby = fminf(a.w, b.w);
    float w = fmaxf(rbx - ltx, 0.0f), h = fmaxf(rby - lty, 0.0f);
    float inter = w * h;
    return inter / (areaA + areaB - inter + 1e-9f);
}

// Kernel 1 (unchanged, proven): 8 threads/box, float4 logit loads.
__global__ void __launch_bounds__(256) k_perbox(const float* __restrict__ boxes,
                                                const float* __restrict__ logits,
                                                const float* __restrict__ gtb,
                                                const int* __restrict__ gtc,
                                                float* __restrict__ score,
                                                float* __restrict__ ce,
                                                unsigned char* __restrict__ label,
                                                u32* __restrict__ done) {
    int tid = threadIdx.x;
    int q = tid & 7;
    int gid = blockIdx.x * 32 + (tid >> 3);
    int b = gid >> 11;
    if (blockIdx.x == 0 && tid == 0) *done = 0;

    float4 bx = ((const float4*)boxes)[gid];
    float best = -1.0f;
    int bg = 0x7FFFFFFF;
    for (int g = q; g < GG; g += 8) {
        float4 gb = ((const float4*)gtb)[b * GG + g];
        float v = iou4(bx, gb);
        if (v > best) { best = v; bg = g; }   // ascending g: strict > = earliest
    }
    for (int d = 1; d < 8; d <<= 1) {
        float vo = __shfl_xor(best, d);
        int go = __shfl_xor(bg, d);
        if (vo > best || (vo == best && go < bg)) { best = vo; bg = go; }
    }
    int assigned = (best >= 0.5f) ? gtc[b * GG + bg] : 80;

    const float* lg = logits + (size_t)gid * CCH;
    uf4 v0 = *(const uf4*)(lg + 4 * q);
    uf4 v1 = *(const uf4*)(lg + 32 + 4 * q);
    bool has2 = (q < 4);
    uf4 v2 = v0;
    if (has2) v2 = *(const uf4*)(lg + 64 + 4 * q);
    float v80 = (q == 7) ? lg[80] : -INFINITY;

    float m = v80, m80 = -INFINITY, la = 0.0f;
    int arg = 0x7FFFFFFF;
    #pragma unroll
    for (int k = 0; k < 4; ++k) {
        float a0 = v0[k]; int c0 = 4 * q + k;
        m = fmaxf(m, a0);
        if (a0 > m80) { m80 = a0; arg = c0; }
        if (c0 == assigned) la = a0;
    }
    #pragma unroll
    for (int k = 0; k < 4; ++k) {
        float a1 = v1[k]; int c1 = 32 + 4 * q + k;
        m = fmaxf(m, a1);
        if (a1 > m80) { m80 = a1; arg = c1; }
        if (c1 == assigned) la = a1;
    }
    if (has2) {
        #pragma unroll
        for (int k = 0; k < 4; ++k) {
            float a2 = v2[k]; int c2 = 64 + 4 * q + k;
            m = fmaxf(m, a2);
            if (a2 > m80) { m80 = a2; arg = c2; }
            if (c2 == assigned) la = a2;
        }
    }
    if (q == 7 && assigned == 80) la = v80;

    for (int d = 1; d < 8; d <<= 1) m = fmaxf(m, __shfl_xor(m, d));

    float s = (q == 7) ? __expf(v80 - m) : 0.0f;
    #pragma unroll
    for (int k = 0; k < 4; ++k) s += __expf(v0[k] - m) + __expf(v1[k] - m);
    if (has2) {
        #pragma unroll
        for (int k = 0; k < 4; ++k) s += __expf(v2[k] - m);
    }
    for (int d = 1; d < 8; d <<= 1) {
        s += __shfl_xor(s, d);
        float m80o = __shfl_xor(m80, d);
        int argo = __shfl_xor(arg, d);
        if (m80o > m80 || (m80o == m80 && argo < arg)) { m80 = m80o; arg = argo; }
        la += __shfl_xor(la, d);
    }
    if (q == 0) {
        float sc = __expf(m80 - m) / s;
        ce[gid] = (m + __logf(s)) - la;
        score[gid] = sc;
        label[gid] = (sc >= 0.05f) ? (unsigned char)arg : (unsigned char)0xFF;
    }
}

// Kernel 2 v3: label-only scan (2KB/block), candidate INDICES to LDS, one
// parallel scattered score gather, then register bitonic + suppression.
__global__ void __launch_bounds__(64) k_nms(const float* __restrict__ boxes,
                                            const float* __restrict__ score,
                                            const unsigned char* __restrict__ label,
                                            u64* __restrict__ klist,
                                            u32* __restrict__ kcnt) {
    __shared__ u16 cidx[128];
    int b = blockIdx.x / NCLS;
    int c = blockIdx.x % NCLS;
    int lane = threadIdx.x;

    // coalesced label load: 8 words per lane (whole image, 2 KB)
    const u32* lab32 = (const u32*)(label + b * NN);
    u32 lw[8];
    #pragma unroll
    for (int ch = 0; ch < 8; ++ch) lw[ch] = lab32[ch * 64 + lane];

    // match count -> exclusive scan -> scatter indices
    int cntl = 0;
    #pragma unroll
    for (int ch = 0; ch < 8; ++ch)
        #pragma unroll
        for (int jj = 0; jj < 4; ++jj)
            cntl += (((lw[ch] >> (8 * jj)) & 0xFFu) == (u32)c) ? 1 : 0;
    int incl = cntl;
    for (int d = 1; d < 64; d <<= 1) {
        int o = __shfl_up(incl, d);
        if (lane >= d) incl += o;
    }
    int k = __shfl(incl, 63);
    int off = incl - cntl;
    #pragma unroll
    for (int ch = 0; ch < 8; ++ch) {
        #pragma unroll
        for (int jj = 0; jj < 4; ++jj) {
            if (((lw[ch] >> (8 * jj)) & 0xFFu) == (u32)c) {
                if (off < 128) cidx[off] = (u16)(4 * (ch * 64 + lane) + jj);
                ++off;
            }
        }
    }
    if (k > 128) k = 128;
    __syncthreads();                         // single wave: cheap

    u64 m0 = 0, m1 = 0;
    u64 key0 = 0, key1 = 0;
    if (k > 0 && k <= 64) {
        // ---------- fast path (statistically always) ----------
        if (lane < k) {
            int i = (int)cidx[lane];
            key0 = ((u64)(__float_as_uint(score[b * NN + i]) | 0x80000000u) << 32) |
                   (u64)(0xFFFFFFFFu - (u32)i);   // one parallel scattered gather
        }
        for (int kk = 2; kk <= 64; kk <<= 1) {
            for (int j = kk >> 1; j > 0; j >>= 1) {
                bool lower = (lane & j) == 0;
                bool dir = ((lane & kk) == 0);
                u64 p = __shfl_xor(key0, j);
                bool t = lower ? (dir ? (p > key0) : (p < key0))
                               : (dir ? (p < key0) : (p > key0));
                if (t) key0 = p;
            }
        }
        bool val0 = lane < k;
        u32 idx0 = 0xFFFFFFFFu - (u32)(key0 & 0xFFFFFFFFull);
        float4 B0 = val0 ? ((const float4*)boxes)[b * NN + idx0]
                         : make_float4(0.f, 0.f, 0.f, 0.f);
        bool sup0 = false;
        for (int i = 0; i < k - 1; ++i) {
            u64 sm0 = __ballot(sup0);
            if ((sm0 >> i) & 1ull) continue;  // uniform
            float4 A;
            A.x = __shfl(B0.x, i); A.y = __shfl(B0.y, i);
            A.z = __shfl(B0.z, i); A.w = __shfl(B0.w, i);
            if (val0 && lane > i && !sup0 && iou4(A, B0) > 0.5f) sup0 = true;
        }
        m0 = __ballot(val0 && !sup0);
    } else if (k > 64) {
        // ---------- slow path (correctness insurance) ----------
        {
            int i0 = (int)cidx[lane];
            key0 = ((u64)(__float_as_uint(score[b * NN + i0]) | 0x80000000u) << 32) |
                   (u64)(0xFFFFFFFFu - (u32)i0);
            if (64 + lane < k) {
                int i1 = (int)cidx[64 + lane];
                key1 = ((u64)(__float_as_uint(score[b * NN + i1]) | 0x80000000u) << 32) |
                       (u64)(0xFFFFFFFFu - (u32)i1);
            }
        }
        for (int kk = 2; kk <= 128; kk <<= 1) {
            for (int j = kk >> 1; j > 0; j >>= 1) {
                if (j == 64) {
                    u64 lo = key0 >= key1 ? key0 : key1;
                    u64 hi = key0 >= key1 ? key1 : key0;
                    key0 = lo; key1 = hi;
                } else {
                    bool lower = (lane & j) == 0;
                    bool dir0 = ((lane & kk) == 0);
                    bool dir1 = (((64 + lane) & kk) == 0);
                    u64 p0 = __shfl_xor(key0, j);
                    u64 p1 = __shfl_xor(key1, j);
                    bool t0 = lower ? (dir0 ? (p0 > key0) : (p0 < key0))
                                    : (dir0 ? (p0 < key0) : (p0 > key0));
                    bool t1 = lower ? (dir1 ? (p1 > key1) : (p1 < key1))
                                    : (dir1 ? (p1 < key1) : (p1 > key1));
                    if (t0) key0 = p0;
                    if (t1) key1 = p1;
                }
            }
        }
        bool val0 = true;
        bool val1 = (64 + lane) < k;
        u32 idx0 = 0xFFFFFFFFu - (u32)(key0 & 0xFFFFFFFFull);
        u32 idx1 = 0xFFFFFFFFu - (u32)(key1 & 0xFFFFFFFFull);
        float4 B0 = ((const float4*)boxes)[b * NN + idx0];
        float4 B1 = val1 ? ((const float4*)boxes)[b * NN + idx1]
                         : make_float4(0.f, 0.f, 0.f, 0.f);
        bool sup0 = false, sup1 = false;
        for (int i = 0; i < k; ++i) {
            u64 sm0 = __ballot(sup0);
            u64 sm1 = __ballot(sup1);
            bool supi = (i < 64) ? ((sm0 >> i) & 1ull) : ((sm1 >> (i - 64)) & 1ull);
            if (supi) continue;              // uniform
            int sl = i & 63;
            float ax = __shfl(i < 64 ? B0.x : B1.x, sl);
            float ay = __shfl(i < 64 ? B0.y : B1.y, sl);
            float az = __shfl(i < 64 ? B0.z : B1.z, sl);
            float aw = __shfl(i < 64 ? B0.w : B1.w, sl);
            float4 A; A.x = ax; A.y = ay; A.z = az; A.w = aw;
            if (val0 && lane > i && !sup0 && iou4(A, B0) > 0.5f) sup0 = true;
            if (val1 && (64 + lane) > i && !sup1 && iou4(A, B1) > 0.5f) sup1 = true;
        }
        m0 = __ballot(val0 && !sup0);
        m1 = __ballot(val1 && !sup1);
    }

    // fixed-slot output: kept keys in descending order, plain stores
    u64 below = (1ull << lane) - 1ull;
    int kept0 = __popcll(m0);
    u64* dst = klist + (size_t)(b * NCLS + c) * SLOTS;
    if ((m0 >> lane) & 1ull) {
        int r = __popcll(m0 & below);
        if (r < SLOTS) dst[r] = key0;
    }
    if ((m1 >> lane) & 1ull) {
        int r = kept0 + __popcll(m1 & below);
        if (r < SLOTS) dst[r] = key1;
    }
    if (lane == 0) {
        int tot = kept0 + __popcll(m1);
        kcnt[b * NCLS + c] = (u32)(tot < SLOTS ? tot : SLOTS);
    }
}

// Kernel 3 v2: parallel prefix scan for class bases; ce prefetched to LDS at
// compact time (one parallel gather) so the tournament never touches global.
__global__ void __launch_bounds__(256) k_select(const u64* __restrict__ klist,
                                                const u32* __restrict__ kcnt,
                                                const float* __restrict__ ce,
                                                float* __restrict__ partial,
                                                u32* __restrict__ done,
                                                float* __restrict__ out) {
    __shared__ u64 skey[NN];
    __shared__ float sce[NN];
    __shared__ int cnts_s[NCLS];
    __shared__ int scan_s[128];
    __shared__ u64 wmax[4];
    __shared__ int wslot[4];
    int b = blockIdx.x;
    int tid = threadIdx.x;
    int lane = tid & 63, wid = tid >> 6;

    if (tid < NCLS) cnts_s[tid] = (int)kcnt[b * NCLS + tid];
    __syncthreads();
    // Hillis-Steele inclusive scan over classes 1..79 (class 0 excluded)
    if (tid < 128) scan_s[tid] = (tid >= 1 && tid < NCLS) ? cnts_s[tid] : 0;
    __syncthreads();
    for (int d = 1; d < 128; d <<= 1) {
        int t2 = 0;
        if (tid < 128 && tid >= d) t2 = scan_s[tid - d];
        __syncthreads();
        if (tid < 128) scan_s[tid] += t2;
        __syncthreads();
    }
    int n = scan_s[NCLS - 1];                 // total kept objects
    int hc = cnts_s[0];
    int hm = hc < 10 ? hc : 10;

    // compact object keys + prefetch their ce into LDS
    for (int idx = tid; idx < (NCLS - 1) * SLOTS; idx += 256) {
        int c = 1 + (idx >> 6), s = idx & (SLOTS - 1);
        if (s < cnts_s[c]) {
            u64 key = klist[(size_t)(b * NCLS + c) * SLOTS + s];
            int slot = (scan_s[c] - cnts_s[c]) + s;   // class base + s
            skey[slot] = key;
            sce[slot] = ce[b * NN + (0xFFFFFFFFu - (u32)(key & 0xFFFFFFFFull))];
        }
    }

    // humans: parallel gather, ordered accumulate on wave 0
    float hsum = 0.0f;
    {
        float hv = 0.0f;
        if (tid < hm) {
            u32 idx = 0xFFFFFFFFu -
                      (u32)(klist[(size_t)(b * NCLS) * SLOTS + tid] & 0xFFFFFFFFull);
            hv = ce[b * NN + idx];
        }
        if (wid == 0)
            for (int r = 0; r < hm; ++r) hsum += __shfl(hv, r);  // descending order
    }
    __syncthreads();

    // objects: tournament top-10 by key (descending), ce from LDS
    int om = n < 10 ? n : 10;
    float osum = 0.0f;
    if (om > 0) {
        u64 ck = 0; int cs = -1;
        for (int s = tid; s < n; s += 256) {
            u64 v = skey[s];
            if (v > ck) { ck = v; cs = s; }
        }
        for (int t = 0; t < om; ++t) {
            u64 k2 = ck; int s2 = cs;
            for (int d = 1; d < 64; d <<= 1) {
                u64 ok = __shfl_xor(k2, d);
                int os = __shfl_xor(s2, d);
                if (ok > k2) { k2 = ok; s2 = os; }
            }
            if (lane == 0) { wmax[wid] = k2; wslot[wid] = s2; }
            __syncthreads();
            u64 bk = wmax[0]; int bs = wslot[0];
            for (int w = 1; w < 4; ++w)
                if (wmax[w] > bk) { bk = wmax[w]; bs = wslot[w]; }
            osum += sce[bs];                  // uniform; keys unique
            if (cs == bs) {
                skey[bs] = 0;
                ck = 0; cs = -1;
                for (int s = tid; s < n; s += 256) {
                    u64 v = skey[s];
                    if (v > ck) { ck = v; cs = s; }
                }
            }
            __syncthreads();
        }
    }

    if (tid == 0) {
        ((volatile float*)partial)[b * 2 + 0] = hsum + osum;
        ((volatile float*)partial)[b * 2 + 1] = (float)(hm + om);
        __threadfence();
        u32 t = atomicAdd(done, 1u);
        if (t == BB - 1) {
            __threadfence();
            float cs2 = 0.0f, cn = 0.0f;
            for (int i = 0; i < BB; ++i) {
                cs2 += ((volatile float*)partial)[i * 2 + 0];
                cn += ((volatile float*)partial)[i * 2 + 1];
            }
            out[0] = cs2 / fmaxf(cn, 1.0f);
        }
    }
}

extern "C" void kernel_launch(void* const* d_in, const int* in_sizes, int n_in,
                              void* d_out, int out_size, void* d_ws, size_t ws_size,
                              hipStream_t stream) {
    const float* boxes = (const float*)d_in[0];       // (16,2048,4)
    const float* logits = (const float*)d_in[1];      // (16,2048,81)
    const float* gt_boxes = (const float*)d_in[2];    // (16,16,4)
    const int* gt_classes = (const int*)d_in[3];      // (16,16)
    float* out = (float*)d_out;

    char* ws = (char*)d_ws;
    size_t off = 0;
    auto alloc = [&](size_t bytes) {
        char* p = ws + off;
        off = (off + bytes + 255) & ~(size_t)255;
        return p;
    };
    float* score = (float*)alloc(BB * NN * sizeof(float));
    float* ce = (float*)alloc(BB * NN * sizeof(float));
    unsigned char* label = (unsigned char*)alloc(BB * NN);
    u64* klist = (u64*)alloc((size_t)BB * NCLS * SLOTS * sizeof(u64));
    u32* kcnt = (u32*)alloc(BB * NCLS * sizeof(u32));
    float* partial = (float*)alloc(BB * 2 * sizeof(float));
    u32* done = (u32*)alloc(sizeof(u32));

    k_perbox<<<BB * NN / 32, 256, 0, stream>>>(boxes, logits, gt_boxes, gt_classes,
                                               score, ce, label, done);
    k_nms<<<BB * NCLS, 64, 0, stream>>>(boxes, score, label, klist, kcnt);
    k_select<<<BB, 256, 0, stream>>>(klist, kcnt, ce, partial, done, out);
}